// Round 1
// baseline (884.769 us; speedup 1.0000x reference)
//
#include <hip/hip_runtime.h>

#define NB 16
#define OUTD 128
#define KF 31

// Block = 256 threads handles a tile of 256 edges.
// Phase 1: thread t computes features of edge tile*256+t into LDS (k4-major float4 layout).
// Phase 2: thread owns 2 output columns (W cols in 62 VGPRs); 64 passes of 4 edges each;
//          feats come from wave-uniform ds_read_b128 broadcasts; stores are row-contiguous.
__global__ __launch_bounds__(256, 4) void geom_kernel(
    const float* __restrict__ frame_t,
    const float* __restrict__ frame_R,
    const int*   __restrict__ edge_src,
    const int*   __restrict__ edge_dst,
    const float* __restrict__ W,
    float*       __restrict__ out,
    int E)
{
    __shared__ float4 sfeat[8 * 256];   // 32 KB: sfeat[k4*256 + edge_local]

    const int tid = threadIdx.x;
    const int jg  = tid & 63;   // column-pair index: owns cols 2*jg, 2*jg+1
    const int wv  = tid >> 6;   // wave id 0..3

    // ---- W columns into registers (persist whole kernel): 62 VGPRs ----
    float w0[KF], w1[KF];
    {
        const float* Wr0 = W + (size_t)(2 * jg) * KF;   // row-major W[128][31]
        #pragma unroll
        for (int k = 0; k < KF; ++k) { w0[k] = Wr0[k]; w1[k] = Wr0[k + KF]; }
    }

    const int ebase = blockIdx.x << 8;
    const int e = ebase + tid;

    // ---- Phase 1: features ----
    float fr[32];
    #pragma unroll
    for (int k = 0; k < 32; ++k) fr[k] = 0.0f;

    if (e < E) {
        const int s = edge_src[e];
        const int d = edge_dst[e];
        const float* tps = frame_t + 3 * (size_t)s;
        const float* tpd = frame_t + 3 * (size_t)d;
        const float dx = tps[0] - tpd[0];
        const float dy = tps[1] - tpd[1];
        const float dz = tps[2] - tpd[2];
        const float dist2 = dx*dx + dy*dy + dz*dz;
        const float dist  = sqrtf(dist2);
        const float inv   = rsqrtf(dist2 + 1.0f);   // 1/sqrt(d^2+1)

        const float step = 20.0f / 15.0f;           // linspace(0,20,16) spacing
        #pragma unroll
        for (int b = 0; b < NB; ++b) {
            const float dv = dist - step * (float)b;
            fr[b] = __expf(-dv * dv);
        }

        const float* Rsp = frame_R + 9 * (size_t)s;
        const float* Rdp = frame_R + 9 * (size_t)d;
        float rs[9], rd[9];
        #pragma unroll
        for (int i = 0; i < 9; ++i) { rs[i] = Rsp[i]; rd[i] = Rdp[i]; }

        // dir_l[j] = -((diff)^T R_s)[j] * inv ; dir_r[j] = ((diff)^T R_d)[j] * inv
        #pragma unroll
        for (int j = 0; j < 3; ++j) {
            const float vl = dx*rs[j] + dy*rs[3+j] + dz*rs[6+j];
            const float vr = dx*rd[j] + dy*rd[3+j] + dz*rd[6+j];
            fr[16 + j] = -vl * inv;
            fr[19 + j] =  vr * inv;
        }
        // orient[i][j] = sum_k R_s[k][i] * R_d[k][j]
        #pragma unroll
        for (int i = 0; i < 3; ++i) {
            #pragma unroll
            for (int j = 0; j < 3; ++j) {
                fr[22 + 3*i + j] = rs[i]*rd[j] + rs[3+i]*rd[3+j] + rs[6+i]*rd[6+j];
            }
        }
    }

    #pragma unroll
    for (int k4 = 0; k4 < 8; ++k4)
        sfeat[k4 * 256 + tid] = make_float4(fr[4*k4], fr[4*k4+1], fr[4*k4+2], fr[4*k4+3]);

    __syncthreads();

    // ---- Phase 2: matmul, 64 passes x 4 edges ----
    for (int p = 0; p < 64; ++p) {
        const int el = (p << 2) | wv;          // wave-uniform edge index within tile

        float4 f4[8];
        #pragma unroll
        for (int k4 = 0; k4 < 8; ++k4) f4[k4] = sfeat[k4 * 256 + el];  // broadcast reads

        float fs[32];
        #pragma unroll
        for (int k4 = 0; k4 < 8; ++k4) {
            fs[4*k4+0] = f4[k4].x; fs[4*k4+1] = f4[k4].y;
            fs[4*k4+2] = f4[k4].z; fs[4*k4+3] = f4[k4].w;
        }

        float a0 = 0.0f, a1 = 0.0f;
        #pragma unroll
        for (int k = 0; k < KF; ++k) {
            a0 = fmaf(fs[k], w0[k], a0);
            a1 = fmaf(fs[k], w1[k], a1);
        }

        const int eg = ebase + el;
        if (eg < E) {
            float2* orow = (float2*)(out + (size_t)eg * OUTD);
            orow[jg] = make_float2(a0, a1);    // 64 lanes -> 512B contiguous
        }
    }
}

extern "C" void kernel_launch(void* const* d_in, const int* in_sizes, int n_in,
                              void* d_out, int out_size, void* d_ws, size_t ws_size,
                              hipStream_t stream) {
    const float* frame_t = (const float*)d_in[0];
    const float* frame_R = (const float*)d_in[1];
    const int*   esrc    = (const int*)d_in[2];
    const int*   edst    = (const int*)d_in[3];
    const float* W       = (const float*)d_in[4];
    float*       out     = (float*)d_out;

    const int E = in_sizes[2];
    const int tiles = (E + 255) / 256;
    hipLaunchKernelGGL(geom_kernel, dim3(tiles), dim3(256), 0, stream,
                       frame_t, frame_R, esrc, edst, W, out, E);
}